// Round 1
// 147.653 us; speedup vs baseline: 1.0918x; 1.0918x over previous
//
#include <hip/hip_runtime.h>

#define K_CODES 512
#define DIM 64
#define HW 1024
#define NVEC 65536
#define NREP 4

// Output offsets (flat concat, reference return order)
#define O0 0             // loss (1)
#define O1 1             // out_q NCHW (4194304)
#define O2 4194305       // perplexity (1)
#define O3 4194306       // idx as float (65536)
#define O4 4259842       // new_cs (512)
#define O5 4260354       // new_ema_w (32768)
#define O6 4293122       // new_embedding (32768)

// ws float layout:
// [0..512)      = per-block loss partials
// [512..1024)   = ee (||e_k||^2)
// [1024..3072)  = counts, 4 replicas x 512 (int)
// [4096..135168)= dw, 4 replicas x 32768
// [135168..)    = B-pack (98304 bf16 = 192KB, MFMA-frag order)
#define WS_LOSS 0
#define WS_EE   512
#define WS_CNT  1024
#define WS_DW   4096
#define WS_BP   135168
#define XSS     72       // padded LDS row stride (floats)

typedef __bf16 bf16x8 __attribute__((ext_vector_type(8)));
typedef float  f32x4  __attribute__((ext_vector_type(4)));

__global__ void k0_init(const float* __restrict__ emb, float* __restrict__ wsf) {
    const int b = blockIdx.x, t = threadIdx.x;
    if (b < 512) {
        wsf[WS_DW + b * 256 + t] = 0.0f;                 // zero 4 dw replicas
    } else if (b == 512) {
        int* cnt = (int*)(wsf + WS_CNT);
        #pragma unroll
        for (int i = 0; i < 8; ++i) cnt[i * 256 + t] = 0; // zero 4 cnt replicas
    } else if (b < 515) {
        int k = (b - 513) * 256 + t;                     // 0..511
        const float* e = emb + k * DIM;
        float s = 0.0f;
        #pragma unroll
        for (int c = 0; c < DIM; ++c) s += e[c] * e[c];
        wsf[WS_EE + k] = s;                              // ||e_k||^2
    } else {
        // Pack bf16 3-way split of (-2*e) into MFMA B-fragment order:
        // frag(s, ntg, ks): lane l holds B^T[code = ntg*16 + (l&15)][c = ks*32 + (l>>4)*8 + j]
        int g = (b - 515) * 256 + t;                     // 0..98303
        int j    = g & 7;
        int lane = (g >> 3) & 63;
        int ks   = (g >> 9) & 1;
        int rest = g >> 10;                              // 0..95
        int ntg  = rest & 31;
        int s    = rest >> 5;                            // split 0..2
        int code = ntg * 16 + (lane & 15);
        int c    = ks * 32 + (lane >> 4) * 8 + j;
        float v = -2.0f * emb[code * DIM + c];
        __bf16 h0 = (__bf16)v;  float r1 = v  - (float)h0;
        __bf16 h1 = (__bf16)r1; float r2 = r1 - (float)h1;
        __bf16 hv = (s == 0) ? h0 : (s == 1 ? h1 : (__bf16)r2);
        ((__bf16*)(wsf + WS_BP))[g] = hv;
    }
}

// Block: 512 threads = 8 waves; 128 vectors x 512 codes per block.
// Wave (mi2 = w&1, ni2 = w>>1): 64-vector x 128-code tile = 4x8 MFMA 16x16 tiles.
__global__ __launch_bounds__(512, 2)
void k1_main(const float* __restrict__ in, const float* __restrict__ emb,
             float* __restrict__ out, float* __restrict__ wsf) {
    __shared__ float xs[128 * XSS];     // fp32 x tile, row=vector, col=c
    __shared__ float pmin[4][128];
    __shared__ int   pidx[4][128];
    __shared__ float xxs[128];
    __shared__ float lsum[2];
    __shared__ int   hist[K_CODES];

    const int t    = threadIdx.x;
    const int lane = t & 63;
    const int wave = t >> 6;           // 0..7
    const int mi2  = wave & 1;         // m half (64 vectors)
    const int ni2  = wave >> 1;        // n quarter (128 codes)
    const int col  = lane & 15;
    const int quad = lane >> 4;

    hist[t] = 0;

    const int blk     = blockIdx.x;
    const int rep     = blk & (NREP - 1);              // atomic replica
    const int n_img   = blk >> 3;
    const int hw_base = (blk & 7) * 128;
    const float* xbase = in + n_img * (DIM * HW) + hw_base;

    // Stage x: 128 vectors x 64 c, coalesced global reads
    #pragma unroll
    for (int rp = 0; rp < 16; ++rp) {
        int e = rp * 512 + t;
        int c = e >> 7, h0 = e & 127;
        xs[h0 * XSS + c] = xbase[c * HW + h0];
    }

    // Accumulators init with ||e||^2 (d = ee - 2<x,e>); all 4 rows share col's code
    f32x4 acc[4][8];
    #pragma unroll
    for (int nt = 0; nt < 8; ++nt) {
        float eev = wsf[WS_EE + ni2 * 128 + nt * 16 + col];
        #pragma unroll
        for (int mi = 0; mi < 4; ++mi) {
            acc[mi][nt][0] = eev; acc[mi][nt][1] = eev;
            acc[mi][nt][2] = eev; acc[mi][nt][3] = eev;
        }
    }

    __syncthreads();

    // ||x||^2 per vector (for loss only; argmin unaffected by +xx)
    if (t < 128) {
        float s = 0.0f;
        #pragma unroll
        for (int c = 0; c < DIM; ++c) { float v = xs[t * XSS + c]; s += v * v; }
        xxs[t] = s;
    }

    const bf16x8* bp8 = (const bf16x8*)(wsf + WS_BP);

    // K-loop: 2 k-steps x 6 split-pairs {(0,0),(1,0),(2,0),(0,1),(1,1),(0,2)}
    #pragma unroll
    for (int ks = 0; ks < 2; ++ks) {
        // Build A splits on the fly from fp32 LDS tile
        bf16x8 A0[4], A1[4], A2[4];
        #pragma unroll
        for (int mi = 0; mi < 4; ++mi) {
            const float* src = &xs[(mi2 * 64 + mi * 16 + col) * XSS + ks * 32 + quad * 8];
            #pragma unroll
            for (int j = 0; j < 8; ++j) {
                float v = src[j];
                __bf16 h0 = (__bf16)v;  float r1 = v  - (float)h0;
                __bf16 h1 = (__bf16)r1; float r2 = r1 - (float)h1;
                A0[mi][j] = h0; A1[mi][j] = h1; A2[mi][j] = (__bf16)r2;
            }
        }
        #pragma unroll
        for (int s = 0; s < 3; ++s) {
            bf16x8 Bv[8];
            #pragma unroll
            for (int nt = 0; nt < 8; ++nt)
                Bv[nt] = bp8[(((s * 32 + ni2 * 8 + nt) * 2 + ks) * 64) + lane];
            #pragma unroll
            for (int mi = 0; mi < 4; ++mi)
                #pragma unroll
                for (int nt = 0; nt < 8; ++nt)
                    acc[mi][nt] = __builtin_amdgcn_mfma_f32_16x16x32_bf16(A0[mi], Bv[nt], acc[mi][nt], 0, 0, 0);
            if (s < 2) {
                #pragma unroll
                for (int mi = 0; mi < 4; ++mi)
                    #pragma unroll
                    for (int nt = 0; nt < 8; ++nt)
                        acc[mi][nt] = __builtin_amdgcn_mfma_f32_16x16x32_bf16(A1[mi], Bv[nt], acc[mi][nt], 0, 0, 0);
            }
            if (s == 0) {
                #pragma unroll
                for (int mi = 0; mi < 4; ++mi)
                    #pragma unroll
                    for (int nt = 0; nt < 8; ++nt)
                        acc[mi][nt] = __builtin_amdgcn_mfma_f32_16x16x32_bf16(A2[mi], Bv[nt], acc[mi][nt], 0, 0, 0);
            }
        }
    }

    // Argmin. C layout: col(code) = lane&15, row(vector) = quad*4 + reg.
    #pragma unroll
    for (int mi = 0; mi < 4; ++mi) {
        #pragma unroll
        for (int r = 0; r < 4; ++r) {
            float v  = acc[mi][0][r];
            int   bi = ni2 * 128 + col;
            #pragma unroll
            for (int nt = 1; nt < 8; ++nt) {            // ascending codes, strict < = first-min
                float u  = acc[mi][nt][r];
                int   ui = ni2 * 128 + nt * 16 + col;
                if (u < v) { v = u; bi = ui; }
            }
            #pragma unroll
            for (int off = 1; off < 16; off <<= 1) {    // 16-lane butterfly, idx tie-break
                float ov = __shfl_xor(v, off);
                int   oi = __shfl_xor(bi, off);
                if (ov < v || (ov == v && oi < bi)) { v = ov; bi = oi; }
            }
            if (col == 0) {
                int row = mi2 * 64 + mi * 16 + quad * 4 + r;
                pmin[ni2][row] = v;
                pidx[ni2][row] = bi;
            }
        }
    }
    __syncthreads();

    // Combine the 4 n-quarters (ascending code ranges), then idx/loss/hist
    if (t < 128) {
        float v = pmin[0][t]; int bi = pidx[0][t];
        #pragma unroll
        for (int q = 1; q < 4; ++q) {
            float u = pmin[q][t]; int ui = pidx[q][t];
            if (u < v) { v = u; bi = ui; }
        }
        pidx[0][t] = bi;                                 // publish final idx
        out[O3 + blk * 128 + t] = (float)bi;
        atomicAdd(&hist[bi], 1);
        float ld = v + xxs[t];                           // d_min = xx + (ee - 2<x,e>)
        #pragma unroll
        for (int off = 32; off > 0; off >>= 1) ld += __shfl_down(ld, off);
        if ((t & 63) == 0) lsum[t >> 6] = ld;            // per-wave partial, no atomic
    }
    __syncthreads();

    if (t == 0) wsf[WS_LOSS + blk] = lsum[0] + lsum[1];  // per-block loss partial (plain store)

    // out_q: thread t -> vector v = t&127, c-quarter t>>7; writes coalesced per c-plane
    {
        int v = t & 127, cq = t >> 7;
        int kv = pidx[0][v];
        const float* ew = emb + kv * DIM;
        float* oq = out + O1 + n_img * (DIM * HW) + hw_base + v;
        #pragma unroll
        for (int c = cq * 16; c < cq * 16 + 16; ++c) oq[c * HW] = ew[c];
    }

    // dw: wave w -> vectors [w*16, w*16+16): coalesced 64-lane atomic row adds
    // into this block's replica (contention / NREP)
    {
        float* dw = wsf + WS_DW + rep * 32768;
        #pragma unroll 1
        for (int v = wave * 16; v < wave * 16 + 16; ++v) {
            int kv = pidx[0][v];
            atomicAdd(&dw[kv * DIM + lane], xs[v * XSS + lane]);
        }
    }

    int* cnt = (int*)(wsf + WS_CNT);
    if (hist[t]) atomicAdd(&cnt[rep * 512 + t], hist[t]);
}

// Merged epilogue: 128 blocks x 256 threads. Each block recomputes the cheap
// 512-wide reductions itself (no cross-block dependency); block 0 additionally
// writes loss / perplexity / new_cs.
__global__ void k2(const float* __restrict__ ema_cs, const float* __restrict__ ema_w,
                   float* __restrict__ out, const float* __restrict__ wsf) {
    __shared__ float s1[256], s2[256];
    const int t = threadIdx.x;
    const int blk = blockIdx.x;
    const int* cnt = (const int*)(wsf + WS_CNT);

    // counts (sum of 4 replicas) for k = t and k = t+256
    float ca = 0.0f, cb = 0.0f;
    #pragma unroll
    for (int r = 0; r < NREP; ++r) {
        ca += (float)cnt[r * 512 + t];
        cb += (float)cnt[r * 512 + 256 + t];
    }
    float ra = 0.99f * ema_cs[t]       + 0.01f * ca;
    float rb = 0.99f * ema_cs[256 + t] + 0.01f * cb;
    float pa = ca * (1.0f / 65536.0f);
    float pb = cb * (1.0f / 65536.0f);
    s1[t] = ra + rb;
    s2[t] = pa * logf(pa + 1e-10f) + pb * logf(pb + 1e-10f);
    __syncthreads();
    for (int s = 128; s > 0; s >>= 1) {
        if (t < s) { s1[t] += s1[t + s]; s2[t] += s2[t + s]; }
        __syncthreads();
    }
    const float n = s1[0];
    const float den = n + 512.0f * 1e-5f;

    // per-block slice of new_ema_w / new_embedding
    {
        int m = blk * 256 + t;                          // 0..32767
        int k = m >> 6;
        float dwsum = wsf[WS_DW + m] + wsf[WS_DW + 32768 + m]
                    + wsf[WS_DW + 65536 + m] + wsf[WS_DW + 98304 + m];
        float w = 0.99f * ema_w[m] + 0.01f * dwsum;
        float ck = 0.0f;
        #pragma unroll
        for (int r = 0; r < NREP; ++r) ck += (float)cnt[r * 512 + k];
        float rawk = 0.99f * ema_cs[k] + 0.01f * ck;
        float csk = (rawk + 1e-5f) / den * n;
        out[O5 + m] = w;
        out[O6 + m] = w / csk;
    }

    if (blk == 0) {
        float s2v = s2[0];
        out[O4 + t]       = (ra + 1e-5f) / den * n;
        out[O4 + 256 + t] = (rb + 1e-5f) / den * n;
        __syncthreads();                                 // done reading s1[0]
        s1[t] = wsf[WS_LOSS + t] + wsf[WS_LOSS + 256 + t];
        __syncthreads();
        for (int s = 128; s > 0; s >>= 1) {
            if (t < s) s1[t] += s1[t + s];
            __syncthreads();
        }
        if (t == 0) {
            out[O0] = 0.25f * s1[0] * (1.0f / 4194304.0f);
            out[O2] = expf(-s2v);
        }
    }
}

extern "C" void kernel_launch(void* const* d_in, const int* in_sizes, int n_in,
                              void* d_out, int out_size, void* d_ws, size_t ws_size,
                              hipStream_t stream) {
    const float* in     = (const float*)d_in[0];   // inputs  (64,64,32,32) NCHW
    const float* emb    = (const float*)d_in[1];   // embedding (512,64)
    const float* ema_w  = (const float*)d_in[2];   // ema_w (512,64)
    const float* ema_cs = (const float*)d_in[3];   // ema_cluster_size (512)
    float* out = (float*)d_out;
    float* wsf = (float*)d_ws;

    hipLaunchKernelGGL(k0_init, dim3(899), dim3(256), 0, stream, emb, wsf);
    hipLaunchKernelGGL(k1_main, dim3(512), dim3(512), 0, stream, in, emb, out, wsf);
    hipLaunchKernelGGL(k2,      dim3(128), dim3(256), 0, stream, ema_cs, ema_w, out, wsf);
}

// Round 2
// 137.091 us; speedup vs baseline: 1.1759x; 1.0770x over previous
//
#include <hip/hip_runtime.h>

#define K_CODES 512
#define DIM 64
#define HW 1024
#define NVEC 65536
#define NREP 4

// Output offsets (flat concat, reference return order)
#define O0 0             // loss (1)
#define O1 1             // out_q NCHW (4194304)
#define O2 4194305       // perplexity (1)
#define O3 4194306       // idx as float (65536)
#define O4 4259842       // new_cs (512)
#define O5 4260354       // new_ema_w (32768)
#define O6 4293122       // new_embedding (32768)

// ws float layout:
// [0..512)        = ee (||e_k||^2)
// [512..2560)     = counts, 4 replicas x 512 (int)
// [2560..4608)    = per-block loss partials (2048)
// [4608..135680)  = dw, 4 replicas x 32768
// [135680..)      = B-pack (98304 bf16, MFMA-frag order)
#define WS_EE   0
#define WS_CNT  512
#define WS_LOSS 2560
#define WS_DW   4608
#define WS_BP   135680

typedef __bf16 bf16x8 __attribute__((ext_vector_type(8)));
typedef float  f32x4  __attribute__((ext_vector_type(4)));

__global__ void k0_init(const float* __restrict__ emb, float* __restrict__ wsf) {
    const int b = blockIdx.x, t = threadIdx.x;
    if (b < 512) {
        wsf[WS_DW + b * 256 + t] = 0.0f;                 // zero 4 dw replicas
    } else if (b == 512) {
        int* cnt = (int*)(wsf + WS_CNT);
        #pragma unroll
        for (int i = 0; i < 8; ++i) cnt[i * 256 + t] = 0; // zero 4 cnt replicas
    } else if (b < 515) {
        int k = (b - 513) * 256 + t;                     // 0..511
        const float* e = emb + k * DIM;
        float s = 0.0f;
        #pragma unroll
        for (int c = 0; c < DIM; ++c) s += e[c] * e[c];
        wsf[WS_EE + k] = s;                              // ||e_k||^2
    } else {
        // Pack bf16 3-way split of (-2*e) into MFMA B-fragment order:
        // frag(s, ntg, ks): lane l holds B^T[code = ntg*16 + (l&15)][c = ks*32 + (l>>4)*8 + j]
        int g = (b - 515) * 256 + t;                     // 0..98303
        int j    = g & 7;
        int lane = (g >> 3) & 63;
        int ks   = (g >> 9) & 1;
        int rest = g >> 10;                              // 0..95
        int ntg  = rest & 31;
        int s    = rest >> 5;                            // split 0..2
        int code = ntg * 16 + (lane & 15);
        int c    = ks * 32 + (lane >> 4) * 8 + j;
        float v = -2.0f * emb[code * DIM + c];
        __bf16 h0 = (__bf16)v;  float r1 = v  - (float)h0;
        __bf16 h1 = (__bf16)r1; float r2 = r1 - (float)h1;
        __bf16 hv = (s == 0) ? h0 : (s == 1 ? h1 : (__bf16)r2);
        ((__bf16*)(wsf + WS_BP))[g] = hv;
    }
}

// Block: 256 threads = 4 waves; 32 vectors x 512 codes per block (2048 blocks).
// Wave ni = wave id: 32-vector x 128-code tile = 2x8 MFMA 16x16 tiles, acc[2][8]=64 AGPR.
// x bf16 3-split computed ONCE into LDS (shared by all waves) -> ds_read_b128 fragments.
__global__ __launch_bounds__(256, 4)
void k1_main(const float* __restrict__ in, const float* __restrict__ emb,
             float* __restrict__ out, float* __restrict__ wsf) {
    __shared__ float xs[32 * 65];            // fp32 x tile, row stride 65
    __shared__ unsigned int xsp[3][32 * 36]; // bf16 splits, packed pairs; row stride 36 uints (144B, 16B-aligned)
    __shared__ float pmin[4][32];
    __shared__ int   pidx[4][32];
    __shared__ float xxs[32];
    __shared__ int   hist[K_CODES];

    const int t    = threadIdx.x;
    const int lane = t & 63;
    const int wave = t >> 6;           // 0..3
    const int ni   = wave;             // 128-code quarter
    const int col  = lane & 15;
    const int quad = lane >> 4;

    hist[t] = 0; hist[t + 256] = 0;

    const int blk     = blockIdx.x;                    // 0..2047
    const int rep     = blk & (NREP - 1);              // atomic replica
    const int n_img   = blk >> 5;
    const int hw_base = (blk & 31) * 32;
    const float* xbase = in + n_img * (DIM * HW) + hw_base;

    // Stage x: 32 vectors x 64 c, coalesced global reads (128B per c-plane)
    #pragma unroll
    for (int it = 0; it < 8; ++it) {
        int e = it * 256 + t;
        int c = e >> 5, h = e & 31;
        xs[h * 65 + c] = xbase[c * HW + h];
    }

    // Accumulators init with ||e||^2 (d = ee - 2<x,e>)
    f32x4 acc[2][8];
    #pragma unroll
    for (int nt = 0; nt < 8; ++nt) {
        float eev = wsf[WS_EE + ni * 128 + nt * 16 + col];
        #pragma unroll
        for (int mi = 0; mi < 2; ++mi) {
            acc[mi][nt][0] = eev; acc[mi][nt][1] = eev;
            acc[mi][nt][2] = eev; acc[mi][nt][3] = eev;
        }
    }

    __syncthreads();

    // Build bf16 3-split of x once (pairs packed into uint), + ||x||^2
    #pragma unroll
    for (int i = 0; i < 4; ++i) {
        int e = i * 256 + t;                 // 0..1023 c-pairs
        int row = e >> 5, cp = e & 31;
        float v0 = xs[row * 65 + 2 * cp];
        float v1 = xs[row * 65 + 2 * cp + 1];
        __bf16 a0 = (__bf16)v0; float ra = v0 - (float)a0;
        __bf16 a1 = (__bf16)ra; ra -= (float)a1;
        __bf16 a2 = (__bf16)ra;
        __bf16 b0 = (__bf16)v1; float rb = v1 - (float)b0;
        __bf16 b1 = (__bf16)rb; rb -= (float)b1;
        __bf16 b2 = (__bf16)rb;
        union { __bf16 h[2]; unsigned int u; } u0, u1, u2;
        u0.h[0] = a0; u0.h[1] = b0;
        u1.h[0] = a1; u1.h[1] = b1;
        u2.h[0] = a2; u2.h[1] = b2;
        xsp[0][row * 36 + cp] = u0.u;
        xsp[1][row * 36 + cp] = u1.u;
        xsp[2][row * 36 + cp] = u2.u;
    }
    if (t < 32) {
        float s = 0.0f;
        #pragma unroll
        for (int c = 0; c < DIM; ++c) { float v = xs[t * 65 + c]; s += v * v; }
        xxs[t] = s;
    }
    __syncthreads();

    const bf16x8* bp8 = (const bf16x8*)(wsf + WS_BP);

    // K-loop: 2 k-steps x 6 split-pairs {(0,0),(1,0),(2,0),(0,1),(1,1),(0,2)}
    #pragma unroll
    for (int ks = 0; ks < 2; ++ks) {
        // A fragments from shared split tile (16B-aligned, even bank spread)
        bf16x8 A0[2], A1[2], A2[2];
        #pragma unroll
        for (int mi = 0; mi < 2; ++mi) {
            int u = (mi * 16 + col) * 36 + ks * 16 + quad * 4;
            A0[mi] = *(const bf16x8*)&xsp[0][u];
            A1[mi] = *(const bf16x8*)&xsp[1][u];
            A2[mi] = *(const bf16x8*)&xsp[2][u];
        }
        #pragma unroll
        for (int s = 0; s < 3; ++s) {
            #pragma unroll
            for (int bh = 0; bh < 2; ++bh) {           // B in halves of 4 (reg pressure)
                bf16x8 Bv[4];
                #pragma unroll
                for (int n4 = 0; n4 < 4; ++n4) {
                    int nt = bh * 4 + n4;
                    Bv[n4] = bp8[(((s * 32 + ni * 8 + nt) * 2 + ks) * 64) + lane];
                }
                #pragma unroll
                for (int mi = 0; mi < 2; ++mi)
                    #pragma unroll
                    for (int n4 = 0; n4 < 4; ++n4)
                        acc[mi][bh * 4 + n4] = __builtin_amdgcn_mfma_f32_16x16x32_bf16(A0[mi], Bv[n4], acc[mi][bh * 4 + n4], 0, 0, 0);
                if (s < 2) {
                    #pragma unroll
                    for (int mi = 0; mi < 2; ++mi)
                        #pragma unroll
                        for (int n4 = 0; n4 < 4; ++n4)
                            acc[mi][bh * 4 + n4] = __builtin_amdgcn_mfma_f32_16x16x32_bf16(A1[mi], Bv[n4], acc[mi][bh * 4 + n4], 0, 0, 0);
                }
                if (s == 0) {
                    #pragma unroll
                    for (int mi = 0; mi < 2; ++mi)
                        #pragma unroll
                        for (int n4 = 0; n4 < 4; ++n4)
                            acc[mi][bh * 4 + n4] = __builtin_amdgcn_mfma_f32_16x16x32_bf16(A2[mi], Bv[n4], acc[mi][bh * 4 + n4], 0, 0, 0);
                }
            }
        }
    }

    // Argmin. C layout: col(code) = lane&15, row(vector) = quad*4 + reg.
    #pragma unroll
    for (int mi = 0; mi < 2; ++mi) {
        #pragma unroll
        for (int r = 0; r < 4; ++r) {
            float v  = acc[mi][0][r];
            int   bi = ni * 128 + col;
            #pragma unroll
            for (int nt = 1; nt < 8; ++nt) {            // ascending codes, strict < = first-min
                float u  = acc[mi][nt][r];
                int   ui = ni * 128 + nt * 16 + col;
                if (u < v) { v = u; bi = ui; }
            }
            #pragma unroll
            for (int off = 1; off < 16; off <<= 1) {    // 16-lane butterfly, idx tie-break
                float ov = __shfl_xor(v, off);
                int   oi = __shfl_xor(bi, off);
                if (ov < v || (ov == v && oi < bi)) { v = ov; bi = oi; }
            }
            if (col == 0) {
                int row = mi * 16 + quad * 4 + r;
                pmin[ni][row] = v;
                pidx[ni][row] = bi;
            }
        }
    }
    __syncthreads();

    // Combine the 4 n-quarters (ascending code ranges), then idx/loss/hist
    if (t < 32) {
        float v = pmin[0][t]; int bi = pidx[0][t];
        #pragma unroll
        for (int q = 1; q < 4; ++q) {
            float u = pmin[q][t]; int ui = pidx[q][t];
            if (u < v) { v = u; bi = ui; }
        }
        pidx[0][t] = bi;                                 // publish final idx
        out[O3 + blk * 32 + t] = (float)bi;
        atomicAdd(&hist[bi], 1);
        float ld = v + xxs[t];                           // d_min = xx + (ee - 2<x,e>)
        #pragma unroll
        for (int off = 16; off > 0; off >>= 1) ld += __shfl_down(ld, off);
        if (t == 0) wsf[WS_LOSS + blk] = ld;             // per-block loss partial
    }
    __syncthreads();

    // out_q: thread t -> vector v = t&31, c-octant t>>5; coalesced per c-plane
    {
        int v = t & 31, cq = t >> 5;
        int kv = pidx[0][v];
        const float* ew = emb + kv * DIM;
        float* oq = out + O1 + n_img * (DIM * HW) + hw_base + v;
        #pragma unroll
        for (int c = cq * 8; c < cq * 8 + 8; ++c) oq[c * HW] = ew[c];
    }

    // dw: wave w -> vectors [w*8, w*8+8): coalesced 64-lane atomic row adds
    {
        float* dw = wsf + WS_DW + rep * 32768;
        #pragma unroll 1
        for (int v = wave * 8; v < wave * 8 + 8; ++v) {
            int kv = pidx[0][v];
            atomicAdd(&dw[kv * DIM + lane], xs[v * 65 + lane]);
        }
    }

    int* cnt = (int*)(wsf + WS_CNT);
    if (hist[t])       atomicAdd(&cnt[rep * 512 + t], hist[t]);
    if (hist[t + 256]) atomicAdd(&cnt[rep * 512 + t + 256], hist[t + 256]);
}

// Merged epilogue: 128 blocks x 256 threads. Each block recomputes the cheap
// 512-wide reductions itself; block 0 additionally writes loss/perplexity/new_cs.
__global__ void k2(const float* __restrict__ ema_cs, const float* __restrict__ ema_w,
                   float* __restrict__ out, const float* __restrict__ wsf) {
    __shared__ float s1[256], s2[256];
    const int t = threadIdx.x;
    const int blk = blockIdx.x;
    const int* cnt = (const int*)(wsf + WS_CNT);

    // counts (sum of 4 replicas) for k = t and k = t+256
    float ca = 0.0f, cb = 0.0f;
    #pragma unroll
    for (int r = 0; r < NREP; ++r) {
        ca += (float)cnt[r * 512 + t];
        cb += (float)cnt[r * 512 + 256 + t];
    }
    float ra = 0.99f * ema_cs[t]       + 0.01f * ca;
    float rb = 0.99f * ema_cs[256 + t] + 0.01f * cb;
    float pa = ca * (1.0f / 65536.0f);
    float pb = cb * (1.0f / 65536.0f);
    s1[t] = ra + rb;
    s2[t] = pa * logf(pa + 1e-10f) + pb * logf(pb + 1e-10f);
    __syncthreads();
    for (int s = 128; s > 0; s >>= 1) {
        if (t < s) { s1[t] += s1[t + s]; s2[t] += s2[t + s]; }
        __syncthreads();
    }
    const float n = s1[0];
    const float den = n + 512.0f * 1e-5f;

    // per-block slice of new_ema_w / new_embedding
    {
        int m = blk * 256 + t;                          // 0..32767
        int k = m >> 6;
        float dwsum = wsf[WS_DW + m] + wsf[WS_DW + 32768 + m]
                    + wsf[WS_DW + 65536 + m] + wsf[WS_DW + 98304 + m];
        float w = 0.99f * ema_w[m] + 0.01f * dwsum;
        float ck = 0.0f;
        #pragma unroll
        for (int r = 0; r < NREP; ++r) ck += (float)cnt[r * 512 + k];
        float rawk = 0.99f * ema_cs[k] + 0.01f * ck;
        float csk = (rawk + 1e-5f) / den * n;
        out[O5 + m] = w;
        out[O6 + m] = w / csk;
    }

    if (blk == 0) {
        float s2v = s2[0];
        out[O4 + t]       = (ra + 1e-5f) / den * n;
        out[O4 + 256 + t] = (rb + 1e-5f) / den * n;
        __syncthreads();                                 // done reading s1[0]
        float lsum = 0.0f;
        #pragma unroll
        for (int j = 0; j < 8; ++j) lsum += wsf[WS_LOSS + j * 256 + t];
        s1[t] = lsum;
        __syncthreads();
        for (int s = 128; s > 0; s >>= 1) {
            if (t < s) s1[t] += s1[t + s];
            __syncthreads();
        }
        if (t == 0) {
            out[O0] = 0.25f * s1[0] * (1.0f / 4194304.0f);
            out[O2] = expf(-s2v);
        }
    }
}

extern "C" void kernel_launch(void* const* d_in, const int* in_sizes, int n_in,
                              void* d_out, int out_size, void* d_ws, size_t ws_size,
                              hipStream_t stream) {
    const float* in     = (const float*)d_in[0];   // inputs  (64,64,32,32) NCHW
    const float* emb    = (const float*)d_in[1];   // embedding (512,64)
    const float* ema_w  = (const float*)d_in[2];   // ema_w (512,64)
    const float* ema_cs = (const float*)d_in[3];   // ema_cluster_size (512)
    float* out = (float*)d_out;
    float* wsf = (float*)d_ws;

    hipLaunchKernelGGL(k0_init, dim3(899),  dim3(256), 0, stream, emb, wsf);
    hipLaunchKernelGGL(k1_main, dim3(2048), dim3(256), 0, stream, in, emb, out, wsf);
    hipLaunchKernelGGL(k2,      dim3(128),  dim3(256), 0, stream, ema_cs, ema_w, out, wsf);
}